// Round 3
// baseline (527.413 us; speedup 1.0000x reference)
//
#include <hip/hip_runtime.h>
#include <math.h>

#define BATCH 64
#define T 256
#define NF 64
#define H 128
#define H4 512                    // 4*H
#define HP1 129
#define WF_STRIDE (HP1 * H4)      // 66048 floats per feature
#define FEATS (NF * H + H)        // 8320
#define NTHREADS 512
#define PACK_UINT4_PER_F 8192     // 16 i * 512 tid
#define PACK_BYTES (64u * PACK_UINT4_PER_F * 16u)   // 8 MB

typedef _Float16 half2_t __attribute__((ext_vector_type(2)));

__device__ __forceinline__ float sigmoidf_(float x) {
    return 1.0f / (1.0f + __expf(-x));
}

__device__ __forceinline__ float tanhf_(float x) {
    float ax = fabsf(x);
    float e = __expf(2.0f * ax);              // inf for large ax -> r = 1
    float r = 1.0f - 2.0f / (e + 1.0f);
    return copysignf(r, x);
}

__device__ __forceinline__ float fdot2_(half2_t a, half2_t b, float c) {
#if defined(__has_builtin)
#if __has_builtin(__builtin_amdgcn_fdot2)
    return __builtin_amdgcn_fdot2(a, b, c, false);
#else
    return fmaf((float)a.x, (float)b.x, fmaf((float)a.y, (float)b.y, c));
#endif
#else
    return fmaf((float)a.x, (float)b.x, fmaf((float)a.y, (float)b.y, c));
#endif
}

// ---------------- repack: W_lin rows 1..128 (h-part) -> fp16 blocked layout ----
// pack[(f*16 + i)*512 + tid] = uint4 of 4 half2:
//   for g in 0..3: ( W[f][1+k0][4*g4+g], W[f][2+k0][4*g4+g] )
//   where kq = tid>>7, g4 = tid&127, k0 = kq*32 + 2*i
__global__ __launch_bounds__(256)
void repack_kernel(const float* __restrict__ W_lin, uint4* __restrict__ pack) {
    const int lin = blockIdx.x * 256 + threadIdx.x;      // 0..524287
    const int f   = lin >> 13;
    const int i   = (lin >> 9) & 15;
    const int tid = lin & 511;
    const int kq  = tid >> 7;
    const int g4  = tid & 127;
    const int k0  = kq * 32 + 2 * i;
    const float* src = W_lin + (size_t)f * WF_STRIDE + (size_t)(1 + k0) * H4 + 4 * g4;
    const float4 r0 = *(const float4*)(src);
    const float4 r1 = *(const float4*)(src + H4);
    half2_t h[4];
    h[0].x = (_Float16)r0.x; h[0].y = (_Float16)r1.x;
    h[1].x = (_Float16)r0.y; h[1].y = (_Float16)r1.y;
    h[2].x = (_Float16)r0.z; h[2].y = (_Float16)r1.z;
    h[3].x = (_Float16)r0.w; h[3].y = (_Float16)r1.w;
    pack[lin] = *(uint4*)h;
}

// ---------------- main scan kernel: depth-2 register prefetch ----------------
__global__ __launch_bounds__(NTHREADS, 2)
void lstm_scan_fp16_kernel(const float* __restrict__ X,
                           const int* __restrict__ lengths,
                           const float* __restrict__ W_lin,
                           const float* __restrict__ b_lin,
                           const float* __restrict__ W_dec,
                           const float* __restrict__ b_dec,
                           const float* __restrict__ W_out,
                           const float* __restrict__ b_out,
                           const uint4* __restrict__ pack,
                           float* __restrict__ out)
{
    __shared__ float s_feats[FEATS];                      // [0,H)=c_t, rest h_t
    __shared__ __align__(16) half2_t s_inp2[H / 2];       // decayed hidden, fp16
    __shared__ float s_part[4][H4];                       // K-split partials
    __shared__ float s_gate[H4];                          // post-nonlinearity gates
    __shared__ float s_X[4 * T];
    __shared__ float s_wdec[NF];
    __shared__ float s_bdec[NF];
    __shared__ float s_red[16];

    float* s_ct = s_feats;
    float* s_ht = s_feats + H;

    const int tid = threadIdx.x;
    const int b   = blockIdx.x;
    const int g4  = tid & 127;
    const int kq  = tid >> 7;

    const float* Xb = X + b * 4 * T;
    const int len = lengths[b];

    for (int i = tid; i < NF * H; i += NTHREADS) s_ht[i] = 0.0f;
    for (int i = tid; i < 4 * T; i += NTHREADS) s_X[i] = Xb[i];
    if (tid < NF) { s_wdec[tid] = W_dec[tid]; s_bdec[tid] = b_dec[tid]; }
    if (tid < H / 2) { half2_t z; z.x = (_Float16)0.0f; z.y = (_Float16)0.0f; s_inp2[tid] = z; }
    __syncthreads();

    float c_t = 0.0f, acc = 0.0f, cnt = 0.0f;

    uint4 bufA[16], bufB[16];
    float b_cur;
    float4 wx;
    float xj_cur;
    // prologue: weights for steps 0 (bufA) and 1 (bufB); bias/x-row/xj for step 0
    {
        const int m0 = (int)Xb[T];
        const int m1v = (int)Xb[T + 1];
        const uint4* Wp0 = pack + m0 * PACK_UINT4_PER_F + tid;
        const uint4* Wp1 = pack + m1v * PACK_UINT4_PER_F + tid;
        #pragma unroll
        for (int i = 0; i < 16; ++i) bufA[i] = Wp0[i * 512];
        #pragma unroll
        for (int i = 0; i < 16; ++i) bufB[i] = Wp1[i * 512];
        b_cur = b_lin[m0 * H4 + tid];
        if (kq == 0) wx = *(const float4*)(W_lin + (size_t)m0 * WF_STRIDE + 4 * g4);
        xj_cur = Xb[2 * T];
    }

    #define STEP(CUR)                                                               \
    {                                                                               \
        const int mj = (int)s_X[T + j];                                             \
        /* load input fragment: 16 half2 via 4 ds_read_b128 */                      \
        half2_t iv[16];                                                             \
        {                                                                           \
            const uint4* ivp = (const uint4*)s_inp2;                                \
            *(uint4*)(&iv[0])  = ivp[kq * 4 + 0];                                   \
            *(uint4*)(&iv[4])  = ivp[kq * 4 + 1];                                   \
            *(uint4*)(&iv[8])  = ivp[kq * 4 + 2];                                   \
            *(uint4*)(&iv[12]) = ivp[kq * 4 + 3];                                   \
        }                                                                           \
        float a0 = 0.0f, a1 = 0.0f, a2 = 0.0f, a3 = 0.0f;                           \
        _Pragma("unroll")                                                           \
        for (int i = 0; i < 16; ++i) {                                              \
            union { uint4 u; half2_t h[4]; } cv;                                    \
            cv.u = CUR[i];                                                          \
            a0 = fdot2_(cv.h[0], iv[i], a0);                                        \
            a1 = fdot2_(cv.h[1], iv[i], a1);                                        \
            a2 = fdot2_(cv.h[2], iv[i], a2);                                        \
            a3 = fdot2_(cv.h[3], iv[i], a3);                                        \
        }                                                                           \
        if (kq == 0) {  /* x-term: fp32 row 0 (prefetched last step) */             \
            a0 = fmaf(xj_cur, wx.x, a0); a1 = fmaf(xj_cur, wx.y, a1);               \
            a2 = fmaf(xj_cur, wx.z, a2); a3 = fmaf(xj_cur, wx.w, a3);               \
        }                                                                           \
        { float4 a4; a4.x = a0; a4.y = a1; a4.z = a2; a4.w = a3;                    \
          *(float4*)(&s_part[kq][4 * g4]) = a4; }                                   \
        /* depth-2 prefetch: weights for j+2 into the just-consumed buffer */       \
        {                                                                           \
            const int j2 = (j + 2 < T) ? (j + 2) : (T - 1);                         \
            const int m2 = (int)s_X[T + j2];                                        \
            const uint4* Wp = pack + m2 * PACK_UINT4_PER_F + tid;                   \
            _Pragma("unroll")                                                       \
            for (int i = 0; i < 16; ++i) CUR[i] = Wp[i * 512];                      \
        }                                                                           \
        /* depth-1 prefetch: bias, x-row, xj for j+1 */                             \
        const int   j1 = (j + 1 < T) ? (j + 1) : (T - 1);                           \
        const int   m1 = (int)s_X[T + j1];                                          \
        const float b_nx = b_lin[m1 * H4 + tid];                                    \
        float4 wx_nx;                                                               \
        if (kq == 0) wx_nx = *(const float4*)(W_lin + (size_t)m1 * WF_STRIDE + 4 * g4); \
        const float xj_nx = s_X[2 * T + j1];                                        \
        __syncthreads();  /* B: partials ready */                                   \
        /* stage1: all 512 threads -> one (gate,h) each, incl. nonlinearity */      \
        {                                                                           \
            const float gsum = s_part[0][tid] + s_part[1][tid]                      \
                             + s_part[2][tid] + s_part[3][tid] + b_cur;             \
            s_gate[tid] = (tid >= 3 * H) ? tanhf_(gsum) : sigmoidf_(gsum);          \
        }                                                                           \
        __syncthreads();  /* C: gates ready */                                      \
        if (tid < H) {                                                              \
            const int h = tid;                                                      \
            const float nl_i = s_gate[h];                                           \
            const float nl_f = s_gate[H + h];                                       \
            const float nl_o = s_gate[2 * H + h];                                   \
            const float nl_c = s_gate[3 * H + h];                                   \
            const float c_cand = nl_f * c_t + nl_i * nl_c;                          \
            const float h_row  = nl_o * tanhf_(c_cand);                             \
            s_ht[mj * H + h] = h_row;                                               \
            acc += c_cand;                                                          \
            cnt += 1.0f;                                                            \
            const float tj = s_X[j];                                                \
            const float tn = (j < T - 1) ? s_X[j + 1] : (tj + 1.0f);                \
            if ((j == len - 1) || (tn != tj)) {                                     \
                c_t = acc / fmaxf(cnt, 1.0f); acc = 0.0f; cnt = 0.0f;               \
            }                                                                       \
            /* produce next step's decayed input (fp16) */                          \
            const float dn  = s_X[3 * T + j1];                                      \
            const float dmn = fmaf(s_wdec[m1], dn, s_bdec[m1]);                     \
            const float den = __expf(-fmaxf(0.0f, dmn));                            \
            const float hv  = (m1 == mj) ? h_row : s_ht[m1 * H + h];                \
            ((_Float16*)s_inp2)[h] = (_Float16)(den * hv);                          \
        }                                                                           \
        __syncthreads();  /* A: s_inp2 + h_t ready */                               \
        b_cur = b_nx;                                                               \
        if (kq == 0) wx = wx_nx;                                                    \
        xj_cur = xj_nx;                                                             \
    }

    int j = 0;
    while (j < len) {
        STEP(bufA); ++j;
        if (j >= len) break;
        STEP(bufB); ++j;
    }
    #undef STEP

    // ---- epilogue: z = feats @ W_out + b_out; softmax over 2 classes ----
    if (tid < H) s_ct[tid] = c_t;
    __syncthreads();

    float z0 = 0.0f, z1 = 0.0f;
    for (int i = tid; i < FEATS; i += NTHREADS) {
        const float f = s_feats[i];
        const float2 w = *(const float2*)(W_out + 2 * i);
        z0 = fmaf(f, w.x, z0);
        z1 = fmaf(f, w.y, z1);
    }
    #pragma unroll
    for (int off = 32; off > 0; off >>= 1) {
        z0 += __shfl_down(z0, off, 64);
        z1 += __shfl_down(z1, off, 64);
    }
    const int wave = tid >> 6, lane = tid & 63;
    if (lane == 0) { s_red[2 * wave] = z0; s_red[2 * wave + 1] = z1; }
    __syncthreads();
    if (tid == 0) {
        float a0 = b_out[0], a1 = b_out[1];
        #pragma unroll
        for (int w = 0; w < 8; ++w) { a0 += s_red[2 * w]; a1 += s_red[2 * w + 1]; }
        const float mx = fmaxf(a0, a1);
        const float e0 = __expf(a0 - mx), e1 = __expf(a1 - mx);
        const float inv = 1.0f / (e0 + e1);
        out[2 * b]     = e0 * inv;
        out[2 * b + 1] = e1 * inv;
    }
}

// ---------------- fp32 fallback (round-1 kernel, used if ws too small) -------
__global__ __launch_bounds__(NTHREADS)
void lstm_scan_kernel(const float* __restrict__ X,
                      const int* __restrict__ lengths,
                      const float* __restrict__ W_lin,
                      const float* __restrict__ b_lin,
                      const float* __restrict__ W_dec,
                      const float* __restrict__ b_dec,
                      const float* __restrict__ W_out,
                      const float* __restrict__ b_out,
                      float* __restrict__ out)
{
    __shared__ float s_feats[FEATS];
    __shared__ float s_inp[H];
    __shared__ float s_part[4][H4];
    __shared__ float s_X[4 * T];
    __shared__ float s_wdec[NF];
    __shared__ float s_bdec[NF];
    __shared__ float s_red[16];

    float* s_ct = s_feats;
    float* s_ht = s_feats + H;

    const int tid = threadIdx.x;
    const int b   = blockIdx.x;
    const int g4  = tid & 127;
    const int kq  = tid >> 7;

    const float* Xb = X + b * 4 * T;
    const int len = lengths[b];

    for (int i = tid; i < NF * H; i += NTHREADS) s_ht[i] = 0.0f;
    for (int i = tid; i < 4 * T; i += NTHREADS) s_X[i] = Xb[i];
    if (tid < NF) { s_wdec[tid] = W_dec[tid]; s_bdec[tid] = b_dec[tid]; }
    __syncthreads();

    float c_t = 0.0f, acc = 0.0f, cnt = 0.0f;

    for (int j = 0; j < len; ++j) {
        const int   mj = (int)s_X[T + j];
        const float xj = s_X[2 * T + j];
        const float* Wf = W_lin + mj * WF_STRIDE;

        float bl0, bl1, bl2, bl3;
        if (tid < H) {
            const float dj    = s_X[3 * T + j];
            const float dm    = fmaf(s_wdec[mj], dj, s_bdec[mj]);
            const float decay = __expf(-fmaxf(0.0f, dm));
            s_inp[tid] = decay * s_ht[mj * H + tid];
            const int m4 = mj * H4;
            bl0 = b_lin[m4 + tid];
            bl1 = b_lin[m4 + H + tid];
            bl2 = b_lin[m4 + 2 * H + tid];
            bl3 = b_lin[m4 + 3 * H + tid];
        }
        __syncthreads();

        float4 a4 = make_float4(0.0f, 0.0f, 0.0f, 0.0f);
        {
            const float*  wr  = Wf + (1 + kq * 32) * H4 + 4 * g4;
            const float4* ivp = (const float4*)(s_inp + kq * 32);
            #pragma unroll
            for (int c = 0; c < 8; ++c) {
                const float4 v = ivp[c];
                const float* wrc = wr + (4 * c) * H4;
                const float4 w0 = *(const float4*)(wrc);
                const float4 w1 = *(const float4*)(wrc + H4);
                const float4 w2 = *(const float4*)(wrc + 2 * H4);
                const float4 w3 = *(const float4*)(wrc + 3 * H4);
                a4.x = fmaf(v.x, w0.x, a4.x); a4.y = fmaf(v.x, w0.y, a4.y);
                a4.z = fmaf(v.x, w0.z, a4.z); a4.w = fmaf(v.x, w0.w, a4.w);
                a4.x = fmaf(v.y, w1.x, a4.x); a4.y = fmaf(v.y, w1.y, a4.y);
                a4.z = fmaf(v.y, w1.z, a4.z); a4.w = fmaf(v.y, w1.w, a4.w);
                a4.x = fmaf(v.z, w2.x, a4.x); a4.y = fmaf(v.z, w2.y, a4.y);
                a4.z = fmaf(v.z, w2.z, a4.z); a4.w = fmaf(v.z, w2.w, a4.w);
                a4.x = fmaf(v.w, w3.x, a4.x); a4.y = fmaf(v.w, w3.y, a4.y);
                a4.z = fmaf(v.w, w3.z, a4.z); a4.w = fmaf(v.w, w3.w, a4.w);
            }
        }
        if (kq == 0) {
            const float4 w = *(const float4*)(Wf + 4 * g4);
            a4.x = fmaf(xj, w.x, a4.x); a4.y = fmaf(xj, w.y, a4.y);
            a4.z = fmaf(xj, w.z, a4.z); a4.w = fmaf(xj, w.w, a4.w);
        }
        *(float4*)(&s_part[kq][4 * g4]) = a4;
        __syncthreads();

        if (tid < H) {
            const int h = tid;
            const float gi = s_part[0][h]         + s_part[1][h]         + s_part[2][h]         + s_part[3][h]         + bl0;
            const float gf = s_part[0][H + h]     + s_part[1][H + h]     + s_part[2][H + h]     + s_part[3][H + h]     + bl1;
            const float go = s_part[0][2*H + h]   + s_part[1][2*H + h]   + s_part[2][2*H + h]   + s_part[3][2*H + h]   + bl2;
            const float gc = s_part[0][3*H + h]   + s_part[1][3*H + h]   + s_part[2][3*H + h]   + s_part[3][3*H + h]   + bl3;

            const float c_cand = sigmoidf_(gf) * c_t + sigmoidf_(gi) * tanhf_(gc);
            const float h_row  = sigmoidf_(go) * tanhf_(c_cand);
            s_ht[mj * H + h] = h_row;
            acc += c_cand;
            cnt += 1.0f;

            const float tj = s_X[j];
            const float tn = (j < T - 1) ? s_X[j + 1] : (tj + 1.0f);
            const bool boundary = (j == len - 1) || (tn != tj);
            if (boundary) { c_t = acc / fmaxf(cnt, 1.0f); acc = 0.0f; cnt = 0.0f; }
        }
        __syncthreads();
    }

    if (tid < H) s_ct[tid] = c_t;
    __syncthreads();

    float z0 = 0.0f, z1 = 0.0f;
    for (int i = tid; i < FEATS; i += NTHREADS) {
        const float f = s_feats[i];
        const float2 w = *(const float2*)(W_out + 2 * i);
        z0 = fmaf(f, w.x, z0);
        z1 = fmaf(f, w.y, z1);
    }
    #pragma unroll
    for (int off = 32; off > 0; off >>= 1) {
        z0 += __shfl_down(z0, off, 64);
        z1 += __shfl_down(z1, off, 64);
    }
    const int wave = tid >> 6, lane = tid & 63;
    if (lane == 0) { s_red[2 * wave] = z0; s_red[2 * wave + 1] = z1; }
    __syncthreads();
    if (tid == 0) {
        float a0 = b_out[0], a1 = b_out[1];
        #pragma unroll
        for (int w = 0; w < 8; ++w) { a0 += s_red[2 * w]; a1 += s_red[2 * w + 1]; }
        const float mx = fmaxf(a0, a1);
        const float e0 = __expf(a0 - mx), e1 = __expf(a1 - mx);
        const float inv = 1.0f / (e0 + e1);
        out[2 * b]     = e0 * inv;
        out[2 * b + 1] = e1 * inv;
    }
}

extern "C" void kernel_launch(void* const* d_in, const int* in_sizes, int n_in,
                              void* d_out, int out_size, void* d_ws, size_t ws_size,
                              hipStream_t stream) {
    const float* X      = (const float*)d_in[0];
    const int*   lens   = (const int*)d_in[1];
    const float* W_lin  = (const float*)d_in[2];
    const float* b_lin  = (const float*)d_in[3];
    const float* W_dec  = (const float*)d_in[4];
    const float* b_dec  = (const float*)d_in[5];
    const float* W_out  = (const float*)d_in[6];
    const float* b_out  = (const float*)d_in[7];
    float* out = (float*)d_out;

    if (ws_size >= (size_t)PACK_BYTES) {
        uint4* pack = (uint4*)d_ws;
        hipLaunchKernelGGL(repack_kernel, dim3(2048), dim3(256), 0, stream, W_lin, pack);
        hipLaunchKernelGGL(lstm_scan_fp16_kernel, dim3(BATCH), dim3(NTHREADS), 0, stream,
                           X, lens, W_lin, b_lin, W_dec, b_dec, W_out, b_out, pack, out);
    } else {
        hipLaunchKernelGGL(lstm_scan_kernel, dim3(BATCH), dim3(NTHREADS), 0, stream,
                           X, lens, W_lin, b_lin, W_dec, b_dec, W_out, b_out, out);
    }
}